// Round 7
// baseline (231.372 us; speedup 1.0000x reference)
//
#include <hip/hip_runtime.h>
#include <math.h>

#define C 256
#define H 40
#define W 40
#define NROI 64
#define PH 7
#define PW 7
#define HW (H * W)
#define NBIN (PH * PW)
#define NPREP 100
#define MAGIC 0x5A17C0DE

// Single fused kernel, 932 blocks:
//   blocks 0..99   : transpose tile + (cy==0) saliency/smax  [r6-proven body]
//   blocks 100..931: wait for all 100 prep flags, then pool   [r6-proven body]
// Handshake: producers __syncthreads -> __threadfence -> agent-scope release
// store of MAGIC; consumers agent-scope acquire polls. Flags need no init:
// ws poison 0xAAAAAAAA != MAGIC. smax via signed atomicMax: poison is negative,
// __float_as_int(s>0) positive -> always replaces poison; idempotent across
// calls since fm is restored identically.
// No-deadlock: __launch_bounds__(256,4) => <=128 VGPR => 4 blocks/CU resident
// (LDS 17.7KB => 9/CU, waves => 8/CU, not binding) => 1024 resident slots >=
// 932 blocks: every block holds a SIMD slot regardless of dispatch order.
__global__ __launch_bounds__(256, 4) void fused_kernel(
    const float* __restrict__ fm, const float* __restrict__ rois1,
    const float* __restrict__ rois2, float* __restrict__ fmT,
    float* __restrict__ sal, int* __restrict__ smax_bits,
    int* __restrict__ flags, float* __restrict__ out) {
  __shared__ float tile[64][65];  // +1 pad: conflict-free both phases
  __shared__ float part[4][64];
  int blk = blockIdx.x;
  int tid = threadIdx.x;

  if (blk < NPREP) {
    // ---------------- prep: transpose fm(C,HW) -> fmT(HW,C) ----------------
    int pt = blk >> 2;
    int cy = blk & 3;
    int p0 = pt * 64, c0 = cy * 64;
#pragma unroll
    for (int it = 0; it < 16; ++it) {
      int idx = it * 256 + tid;
      int cl = idx >> 6;
      int pl = idx & 63;  // lanes vary pixel -> coalesced read
      tile[pl][cl] = fm[(c0 + cl) * HW + p0 + pl];
    }
    __syncthreads();
#pragma unroll
    for (int it = 0; it < 16; ++it) {
      int idx = it * 256 + tid;
      int pl = idx >> 6;
      int cl = idx & 63;  // lanes vary channel -> coalesced write
      fmT[(p0 + pl) * C + c0 + cl] = tile[pl][cl];
    }

    if (cy == 0) {  // block-uniform branch: __syncthreads inside is safe
      int pl = tid & 63, q = tid >> 6;
      float acc = 0.0f;
#pragma unroll 8
      for (int i = 0; i < 64; ++i) acc += fm[(q * 64 + i) * HW + p0 + pl];
      part[q][pl] = acc;
      __syncthreads();
      if (tid < 64) {
        float s = part[0][tid] + part[1][tid] + part[2][tid] + part[3][tid];
        sal[p0 + tid] = s;
        float m = s;
#pragma unroll
        for (int off = 32; off > 0; off >>= 1)
          m = fmaxf(m, __shfl_down(m, off));
        if (tid == 0) atomicMax(smax_bits, __float_as_int(m));
      }
    }
    // ---- publish: all block stores done -> fence -> release flag ----
    __syncthreads();
    if (tid == 0) {
      __threadfence();  // device-scope: drain fmT/sal/smax stores
      __hip_atomic_store(&flags[blk], MAGIC, __ATOMIC_RELEASE,
                         __HIP_MEMORY_SCOPE_AGENT);
    }
    return;
  }

  // ---------------- consumer: wait for all 100 prep flags ----------------
  if (tid < NPREP) {
    while (__hip_atomic_load(&flags[tid], __ATOMIC_ACQUIRE,
                             __HIP_MEMORY_SCOPE_AGENT) != MAGIC) {
      __builtin_amdgcn_s_sleep(1);  // light backoff, reduce L2 poll traffic
    }
  }
  __syncthreads();

  // ---------------- pool: wave = (roi, bin); lane = 4 channels -----------
  int pblk = blk - NPREP;
  int n = pblk / 13;
  int g = pblk - n * 13;
  int w = tid >> 6;
  int l = tid & 63;
  int b = g * 4 + w;
  if (b >= NBIN) return;  // whole-wave exit; no barriers below

  const float4* fmT4 = (const float4*)fmT;
  const float* r1 = rois1 + n * 5;
  const float* r2 = rois2 + n * 5;
  // jnp.round = round-half-to-even = rintf under default rounding mode.
  int x1a = min((int)rintf(r1[1] * 0.0625f), W - 1);
  int y1a = min((int)rintf(r1[2] * 0.0625f), H - 1);
  int x2a = min((int)rintf(r1[3] * 0.0625f), W - 1);
  int y2a = min((int)rintf(r1[4] * 0.0625f), H - 1);
  int x1b = min((int)rintf(r2[1] * 0.0625f), W - 1);
  int y1b = min((int)rintf(r2[2] * 0.0625f), H - 1);
  int x2b = min((int)rintf(r2[3] * 0.0625f), W - 1);
  int y2b = min((int)rintf(r2[4] * 0.0625f), H - 1);

  int ux1 = min(x1a, x1b), uy1 = min(y1a, y1b);
  int ux2 = max(x2a, x2b), uy2 = max(y2a, y2b);
  int hb = uy2 - uy1 + 1, wb = ux2 - ux1 + 1;

  int ph = b / PW, pw = b - (b / PW) * PW;
  int ys0 = uy1 + (ph * hb) / PH;
  int ys1 = uy1 + ((ph + 1) * hb + PH - 1) / PH;
  int xs0 = ux1 + (pw * wb) / PW;
  int xs1 = ux1 + ((pw + 1) * wb + PW - 1) / PW;
  int bw = xs1 - xs0;
  int npx = (ys1 - ys0) * bw;  // >= 1 always (adaptive bins never empty)

  float inv = 1.0f / __int_as_float(*smax_bits);

  int y = ys0, x = xs0;
  int p = y * W + x;
  bool ay = (y >= y1a) & (y <= y2a);
  bool by = (y >= y1b) & (y <= y2b);

  float4 v = fmT4[p * 64 + l];  // lanes contiguous 16B -> 1KB/wave
  float sv = sal[p];            // uniform address broadcast
  bool ins = (ay & (x >= x1a) & (x <= x2a)) | (by & (x >= x1b) & (x <= x2b));
  float4 best = make_float4(-INFINITY, -INFINITY, -INFINITY, -INFINITY);

  for (int i = 1; i < npx; ++i) {
    // advance & issue next pixel's loads (1-deep pipeline)
    ++x;
    ++p;
    if (x == xs1) {  // wave-uniform branch
      x = xs0;
      ++y;
      p += W - bw;
      ay = (y >= y1a) & (y <= y2a);
      by = (y >= y1b) & (y <= y2b);
    }
    float4 vn = fmT4[p * 64 + l];
    float svn = sal[p];
    bool insn =
        (ay & (x >= x1a) & (x <= x2a)) | (by & (x >= x1b) & (x <= x2b));
    // consume current pixel
    float q = sv * inv;
    q = q * q;
    q = q * q;
    float m = ins ? 1.0f : 0.5f + 0.4f * q;
    best.x = fmaxf(best.x, v.x * m);
    best.y = fmaxf(best.y, v.y * m);
    best.z = fmaxf(best.z, v.z * m);
    best.w = fmaxf(best.w, v.w * m);
    v = vn;
    sv = svn;
    ins = insn;
  }
  {
    float q = sv * inv;
    q = q * q;
    q = q * q;
    float m = ins ? 1.0f : 0.5f + 0.4f * q;
    best.x = fmaxf(best.x, v.x * m);
    best.y = fmaxf(best.y, v.y * m);
    best.z = fmaxf(best.z, v.z * m);
    best.w = fmaxf(best.w, v.w * m);
  }

  int obase = (n * C + 4 * l) * NBIN + b;
  out[obase] = best.x;
  out[obase + NBIN] = best.y;
  out[obase + 2 * NBIN] = best.z;
  out[obase + 3 * NBIN] = best.w;
}

extern "C" void kernel_launch(void* const* d_in, const int* in_sizes, int n_in,
                              void* d_out, int out_size, void* d_ws,
                              size_t ws_size, hipStream_t stream) {
  const float* fm = (const float*)d_in[0];
  const float* r1 = (const float*)d_in[1];
  const float* r2 = (const float*)d_in[2];
  float* out = (float*)d_out;

  char* ws = (char*)d_ws;
  float* sal = (float*)ws;                           // 1600 floats @ 0
  int* smax_bits = (int*)(ws + HW * sizeof(float));  // 1 int @ 6400
  int* flags = (int*)(ws + 8192);                    // 100 ints
  float* fmT = (float*)(ws + 16384);                 // HW*C floats, 16B aligned

  fused_kernel<<<NPREP + NROI * 13, 256, 0, stream>>>(
      fm, r1, r2, fmT, sal, smax_bits, flags, out);
}

// Round 8
// 78.461 us; speedup vs baseline: 2.9489x; 2.9489x over previous
//
#include <hip/hip_runtime.h>
#include <math.h>

#define C 256
#define H 40
#define W 40
#define NROI 64
#define PH 7
#define PW 7
#define HW (H * W)
#define NBIN (PH * PW)

// ---------------- Kernel 1: fused transpose + saliency + smax ----------------
// grid 100 = (pixel-tile pt = blk>>2) x (channel-tile cy = blk&3).
// All blocks: LDS-tiled transpose fm(C,HW) -> fmT(HW,C).
// cy==0 blocks additionally: s[p] = sum_c fm[c][p] for their 64 pixels,
// wave-reduce max, atomicMax into smax_bits. No memset needed: ws poison
// 0xAAAAAAAA is a NEGATIVE int, and s>0 so __float_as_int(s) is positive ->
// signed atomicMax always replaces poison; on fresh (un-poisoned) launches the
// leftover value equals the new smax (fm restored identically) -> idempotent.
// NOTE (r7 lesson): do NOT fuse prep+pool into one kernel with a flag
// handshake — measured +112 us of spin-wait vs ~6 us for the node boundary.
__global__ __launch_bounds__(256) void prep_kernel(
    const float* __restrict__ fm, float* __restrict__ fmT,
    float* __restrict__ sal, int* __restrict__ smax_bits) {
  __shared__ float tile[64][65];  // +1 pad: conflict-free both phases
  __shared__ float part[4][64];
  int blk = blockIdx.x;
  int pt = blk >> 2;
  int cy = blk & 3;
  int p0 = pt * 64, c0 = cy * 64;
  int tid = threadIdx.x;

#pragma unroll
  for (int it = 0; it < 16; ++it) {
    int idx = it * 256 + tid;
    int cl = idx >> 6;
    int pl = idx & 63;  // lanes vary pixel -> coalesced read
    tile[pl][cl] = fm[(c0 + cl) * HW + p0 + pl];
  }
  __syncthreads();
#pragma unroll
  for (int it = 0; it < 16; ++it) {
    int idx = it * 256 + tid;
    int pl = idx >> 6;
    int cl = idx & 63;  // lanes vary channel -> coalesced write
    fmT[(p0 + pl) * C + c0 + cl] = tile[pl][cl];
  }

  if (cy == 0) {  // block-uniform branch: __syncthreads inside is safe
    int pl = tid & 63, q = tid >> 6;
    float acc = 0.0f;
#pragma unroll 8
    for (int i = 0; i < 64; ++i) acc += fm[(q * 64 + i) * HW + p0 + pl];
    part[q][pl] = acc;
    __syncthreads();
    if (tid < 64) {
      float s = part[0][tid] + part[1][tid] + part[2][tid] + part[3][tid];
      sal[p0 + tid] = s;
      float m = s;
#pragma unroll
      for (int off = 32; off > 0; off >>= 1) m = fmaxf(m, __shfl_down(m, off));
      if (tid == 0) atomicMax(smax_bits, __float_as_int(m));
    }
  }
}

// ---------------- Kernel 2: pool. wave = (roi, bin); lane = 4 channels -------
// grid 64 x 13 blocks; block 256 thr = 4 waves = 4 bins. One dwordx4 fmT
// load per pixel per wave (coalesced 1KB); mask math issued once per wave.
__global__ __launch_bounds__(256) void pool_kernel(
    const float4* __restrict__ fmT4, const float* __restrict__ rois1,
    const float* __restrict__ rois2, const float* __restrict__ sal,
    const int* __restrict__ smax_bits, float* __restrict__ out) {
  int blk = blockIdx.x;
  int n = blk / 13;
  int g = blk - n * 13;
  int w = threadIdx.x >> 6;
  int l = threadIdx.x & 63;
  int b = g * 4 + w;
  if (b >= NBIN) return;  // whole-wave exit; no barriers below

  const float* r1 = rois1 + n * 5;
  const float* r2 = rois2 + n * 5;
  // jnp.round = round-half-to-even = rintf under default rounding mode.
  int x1a = min((int)rintf(r1[1] * 0.0625f), W - 1);
  int y1a = min((int)rintf(r1[2] * 0.0625f), H - 1);
  int x2a = min((int)rintf(r1[3] * 0.0625f), W - 1);
  int y2a = min((int)rintf(r1[4] * 0.0625f), H - 1);
  int x1b = min((int)rintf(r2[1] * 0.0625f), W - 1);
  int y1b = min((int)rintf(r2[2] * 0.0625f), H - 1);
  int x2b = min((int)rintf(r2[3] * 0.0625f), W - 1);
  int y2b = min((int)rintf(r2[4] * 0.0625f), H - 1);

  int ux1 = min(x1a, x1b), uy1 = min(y1a, y1b);
  int ux2 = max(x2a, x2b), uy2 = max(y2a, y2b);
  int hb = uy2 - uy1 + 1, wb = ux2 - ux1 + 1;

  int ph = b / PW, pw = b - (b / PW) * PW;
  int ys0 = uy1 + (ph * hb) / PH;
  int ys1 = uy1 + ((ph + 1) * hb + PH - 1) / PH;
  int xs0 = ux1 + (pw * wb) / PW;
  int xs1 = ux1 + ((pw + 1) * wb + PW - 1) / PW;
  int bw = xs1 - xs0;
  int npx = (ys1 - ys0) * bw;  // >= 1 always (adaptive bins never empty)

  float inv = 1.0f / __int_as_float(*smax_bits);

  int y = ys0, x = xs0;
  int p = y * W + x;
  bool ay = (y >= y1a) & (y <= y2a);
  bool by = (y >= y1b) & (y <= y2b);

  float4 v = fmT4[p * 64 + l];  // lanes contiguous 16B -> 1KB/wave
  float sv = sal[p];            // uniform address broadcast
  bool ins = (ay & (x >= x1a) & (x <= x2a)) | (by & (x >= x1b) & (x <= x2b));
  float4 best = make_float4(-INFINITY, -INFINITY, -INFINITY, -INFINITY);

  for (int i = 1; i < npx; ++i) {
    // advance & issue next pixel's loads (1-deep pipeline)
    ++x;
    ++p;
    if (x == xs1) {  // wave-uniform branch
      x = xs0;
      ++y;
      p += W - bw;
      ay = (y >= y1a) & (y <= y2a);
      by = (y >= y1b) & (y <= y2b);
    }
    float4 vn = fmT4[p * 64 + l];
    float svn = sal[p];
    bool insn =
        (ay & (x >= x1a) & (x <= x2a)) | (by & (x >= x1b) & (x <= x2b));
    // consume current pixel
    float q = sv * inv;
    q = q * q;
    q = q * q;
    float m = ins ? 1.0f : 0.5f + 0.4f * q;
    best.x = fmaxf(best.x, v.x * m);
    best.y = fmaxf(best.y, v.y * m);
    best.z = fmaxf(best.z, v.z * m);
    best.w = fmaxf(best.w, v.w * m);
    v = vn;
    sv = svn;
    ins = insn;
  }
  {
    float q = sv * inv;
    q = q * q;
    q = q * q;
    float m = ins ? 1.0f : 0.5f + 0.4f * q;
    best.x = fmaxf(best.x, v.x * m);
    best.y = fmaxf(best.y, v.y * m);
    best.z = fmaxf(best.z, v.z * m);
    best.w = fmaxf(best.w, v.w * m);
  }

  int obase = (n * C + 4 * l) * NBIN + b;
  out[obase] = best.x;
  out[obase + NBIN] = best.y;
  out[obase + 2 * NBIN] = best.z;
  out[obase + 3 * NBIN] = best.w;
}

extern "C" void kernel_launch(void* const* d_in, const int* in_sizes, int n_in,
                              void* d_out, int out_size, void* d_ws,
                              size_t ws_size, hipStream_t stream) {
  const float* fm = (const float*)d_in[0];
  const float* r1 = (const float*)d_in[1];
  const float* r2 = (const float*)d_in[2];
  float* out = (float*)d_out;

  char* ws = (char*)d_ws;
  float* sal = (float*)ws;                           // 1600 floats @ 0
  int* smax_bits = (int*)(ws + HW * sizeof(float));  // 1 int @ 6400
  float* fmT = (float*)(ws + 16384);                 // HW*C floats, 16B aligned

  prep_kernel<<<100, 256, 0, stream>>>(fm, fmT, sal, smax_bits);
  pool_kernel<<<NROI * 13, 256, 0, stream>>>((const float4*)fmT, r1, r2, sal,
                                             smax_bits, out);
}